// Round 1
// 781.865 us; speedup vs baseline: 1.0746x; 1.0746x over previous
//
#include <hip/hip_runtime.h>
#include <math.h>

#define NNODES 100000
#define NEDGES 1200000

// fp32 constants, matching the numpy reference's evaluation order/precision
#define C_EC   1.602176634e-19f
#define C_E2   (C_EC * C_EC)                     // fp32 fold, ~2.57e-38 (normal)
#define C_4PI  12.566370614359172f               // np.float32(4*pi)
#define C_EPS0 8.8541878128e-12f
#define C_A    (C_4PI * C_EPS0)
#define C_B    1e-10f

typedef __attribute__((ext_vector_type(8))) short bf16x8;           // 8 bf16 = 4 VGPR
typedef __attribute__((ext_vector_type(4))) float f32x4;            // MFMA C/D
typedef __attribute__((ext_vector_type(4))) unsigned short u16x4;   // 8B packed bf16

// Wave-private LDS handoff ordering: every LDS slice in this file is owned by a
// single wave (slice = wave*16*72), so no s_barrier is needed — only a compiler
// ordering fence so ds_write/ds_read program order is preserved. Emits nothing.
__device__ __forceinline__ void wave_sync() {
    __builtin_amdgcn_fence(__ATOMIC_ACQ_REL, "wavefront");
    __builtin_amdgcn_wave_barrier();
}

__device__ __forceinline__ unsigned short f2bf(float f) {
    unsigned u = __float_as_uint(f);
    u += 0x7fffu + ((u >> 16) & 1u);             // RNE
    return (unsigned short)(u >> 16);
}
__device__ __forceinline__ float bf2f(unsigned short s) {
    return __uint_as_float(((unsigned)s) << 16);
}
__device__ __forceinline__ float softplus_f(float x) {
    return fmaxf(x, 0.0f) + log1pf(__expf(-fabsf(x)));
}
// mish(x) = x*tanh(softplus(x)) = x*(u^2-1)/(u^2+1), u=1+e^x  -> one transcendental.
// Divide -> v_rcp (~1 ulp): result is bf16-rounded right after, so invisible.
__device__ __forceinline__ float mish_f(float x) {
    float e = __expf(fminf(x, 30.0f));           // clamp: mish(x>30)==x in fp32
    float n = e * e + 2.0f * e;
    return x * n * __builtin_amdgcn_rcpf(n + 2.0f);
}

// Feature permutation for HIDDEN tensors: stored col c' = PERM(c) = (c&15)*4 + (c>>4).
// MFMA C/D lane (q,l15) holds cols c = t*16+l15 for t=0..3 -> PERM(c) = l15*4+t, i.e.
// a lane's 4 output values land CONTIGUOUS in storage (8B vector writes, 8B gathers).
// Consuming layers read storage-contiguous K, so their weights are K-permuted in K0.

// ---- one 64->64 linear layer via MFMA, for one wave's 16 rows ----
// xs:  wave's LDS slice, 16 rows x 72 bf16 (stride 72: 144B rows keep b128 aligned)
// wg:  global bf16 weights, W[n][k] with k in the SAME order as the xs columns
// acc[t] covers output cols t*16..t*16+15 (C/D: col=lane&15, row=(lane>>4)*4+reg)
__device__ __forceinline__ void mfma_layer(const unsigned short* xs,
                                           const unsigned short* __restrict__ wg,
                                           const float* __restrict__ bias,
                                           int lane, f32x4 acc[4])
{
    const int l15 = lane & 15, q = lane >> 4;
    bf16x8 a0 = *(const bf16x8*)(xs + l15 * 72 + q * 8);        // A[m=l15][k=q*8+j]
    bf16x8 a1 = *(const bf16x8*)(xs + l15 * 72 + 32 + q * 8);   // k in [32,64)
    #pragma unroll
    for (int t = 0; t < 4; ++t) {
        float bv = bias[t * 16 + l15];           // y = x@W.T + b : bias by col
        acc[t] = (f32x4){bv, bv, bv, bv};
        // B[k][n]=W[n][k]; lane holds k=q*8+j of row n=t*16+l15 -> 16B loads
        bf16x8 b0 = *(const bf16x8*)(wg + (t * 16 + l15) * 64 + q * 8);
        bf16x8 b1 = *(const bf16x8*)(wg + (t * 16 + l15) * 64 + 32 + q * 8);
        acc[t] = __builtin_amdgcn_mfma_f32_16x16x32_bf16(a0, b0, acc[t], 0, 0, 0);
        acc[t] = __builtin_amdgcn_mfma_f32_16x16x32_bf16(a1, b1, acc[t], 0, 0, 0);
    }
}

// mish(acc) -> bf16 into wave's LDS slice, PERMUTED columns: per j one 8B write.
__device__ __forceinline__ void mish_to_lds_perm(const f32x4 acc[4], unsigned short* hid, int lane)
{
    const int l15 = lane & 15, q = lane >> 4;
    #pragma unroll
    for (int j = 0; j < 4; ++j) {
        u16x4 v;
        v[0] = f2bf(mish_f(acc[0][j]));
        v[1] = f2bf(mish_f(acc[1][j]));
        v[2] = f2bf(mish_f(acc[2][j]));
        v[3] = f2bf(mish_f(acc[3][j]));
        *(u16x4*)(hid + (q * 4 + j) * 72 + l15 * 4) = v;       // stored col = PERM(c)
    }
}

// K0: convert the 8 weight matrices fp32 -> bf16.
// Matrices consuming PERMUTED inputs (ws2, wd2, we2, wm1, wm2 = m 1,3,5,6,7) get
// their K axis permuted in storage: wbf[n*64 + PERM(k)] = W[n][k].
__global__ __launch_bounds__(256) void convert_w_kernel(
    const float* __restrict__ w0, const float* __restrict__ w1,
    const float* __restrict__ w2, const float* __restrict__ w3,
    const float* __restrict__ w4, const float* __restrict__ w5,
    const float* __restrict__ w6, const float* __restrict__ w7,
    unsigned short* __restrict__ wbf)
{
    int g = blockIdx.x * 256 + threadIdx.x;      // 8192 threads x 4 elems
    int m = g >> 10;
    int e = (g & 1023) * 4;
    const float* w;
    switch (m) {
        case 0: w = w0; break; case 1: w = w1; break;
        case 2: w = w2; break; case 3: w = w3; break;
        case 4: w = w4; break; case 5: w = w5; break;
        case 6: w = w6; break; default: w = w7; break;
    }
    float4 v = *(const float4*)(w + e);
    int n = e >> 6, k = e & 63;                  // k % 4 == 0
    bool perm = (m == 1) || (m == 3) || (m >= 5);
    int kk = perm ? ((k & 15) * 4 + (k >> 4)) : k;
    int st = perm ? 4 : 1;                       // PERM(k+i) = PERM(k) + 4i (k%4==0)
    unsigned short* dp = wbf + m * 4096 + n * 64 + kk;
    dp[0] = f2bf(v.x); dp[st] = f2bf(v.y); dp[2 * st] = f2bf(v.z); dp[3 * st] = f2bf(v.w);
}

// K1: fused ws+wd node MLPs -> hs, hd (bf16, PERMUTED feature storage).
// All LDS slices wave-private -> no __syncthreads at all. Also zeroes d_out
// (replaces the memset dispatch).
__global__ __launch_bounds__(256) void node_mlp_kernel(
    const float* __restrict__ x,
    const unsigned short* __restrict__ wbf,
    const float* __restrict__ bs1, const float* __restrict__ bs2,
    const float* __restrict__ bd1, const float* __restrict__ bd2,
    unsigned short* __restrict__ hs, unsigned short* __restrict__ hd,
    float* __restrict__ out)
{
    __shared__ __align__(16) unsigned short xs[64 * 72];
    __shared__ __align__(16) unsigned short hid[64 * 72];
    const int t = threadIdx.x, lane = t & 63, wave = t >> 6;
    const int row0 = blockIdx.x * 64 + wave * 16;
    unsigned short* xw = xs + wave * 16 * 72;
    unsigned short* hw = hid + wave * 16 * 72;
    const int l15 = lane & 15, q = lane >> 4;

    // zero this block's output rows (fire-and-forget stores)
    {
        int r = lane >> 2, c4 = lane & 3;
        if (row0 + r < NNODES) {
            float4 z = make_float4(0.f, 0.f, 0.f, 0.f);
            #pragma unroll
            for (int i = 0; i < 4; ++i)
                *(float4*)(out + (size_t)(row0 + r) * 64 + (c4 + i * 4) * 4) = z;
        }
    }

    // stage 16 rows fp32 -> bf16 (zero-pad past NNODES), standard column order
    {
        int r = lane >> 2, c4 = lane & 3;
        #pragma unroll
        for (int i = 0; i < 4; ++i) {
            int col = (c4 + i * 4) * 4;
            float4 v = make_float4(0.f, 0.f, 0.f, 0.f);
            if (row0 + r < NNODES) v = *(const float4*)(x + (size_t)(row0 + r) * 64 + col);
            unsigned short* dp = xw + r * 72 + col;
            dp[0] = f2bf(v.x); dp[1] = f2bf(v.y); dp[2] = f2bf(v.z); dp[3] = f2bf(v.w);
        }
    }
    wave_sync();                                       // xs staged -> readable

    f32x4 acc[4];
    // ws net
    mfma_layer(xw, wbf + 0 * 4096, bs1, lane, acc);    // std weights
    wave_sync();
    mish_to_lds_perm(acc, hw, lane);
    wave_sync();                                       // hid written -> readable
    mfma_layer(hw, wbf + 1 * 4096, bs2, lane, acc);    // K-permuted weights
    #pragma unroll
    for (int j = 0; j < 4; ++j) {
        int row = row0 + q * 4 + j;
        if (row < NNODES) {
            u16x4 v;
            v[0] = f2bf(acc[0][j]); v[1] = f2bf(acc[1][j]);
            v[2] = f2bf(acc[2][j]); v[3] = f2bf(acc[3][j]);
            *(u16x4*)(hs + (size_t)row * 64 + l15 * 4) = v;    // permuted cols, 8B
        }
    }
    // wd net (xs tile untouched)
    mfma_layer(xw, wbf + 2 * 4096, bd1, lane, acc);    // std weights
    wave_sync();                                       // retire hid reads (WAR)
    mish_to_lds_perm(acc, hw, lane);
    wave_sync();                                       // hid written -> readable
    mfma_layer(hw, wbf + 3 * 4096, bd2, lane, acc);    // K-permuted weights
    #pragma unroll
    for (int j = 0; j < 4; ++j) {
        int row = row0 + q * 4 + j;
        if (row < NNODES) {
            u16x4 v;
            v[0] = f2bf(acc[0][j]); v[1] = f2bf(acc[1][j]);
            v[2] = f2bf(acc[2][j]); v[3] = f2bf(acc[3][j]);
            *(u16x4*)(hd + (size_t)row * 64 + l15 * 4) = v;
        }
    }
}

// K2: fused edge pipeline, 64 edges/block, wave-owned rows, no __syncthreads.
// hs/hd gathers are 8B vector loads issued BEFORE the we-MLP (latency hidden).
__global__ __launch_bounds__(256) void edge_kernel(
    const float* __restrict__ efeat,
    const unsigned short* __restrict__ hs, const unsigned short* __restrict__ hd,
    const int* __restrict__ src, const int* __restrict__ dst,
    const unsigned short* __restrict__ wbf,
    const float* __restrict__ be1, const float* __restrict__ be2,
    const float* __restrict__ bm1, const float* __restrict__ bm2,
    float* __restrict__ out)
{
    __shared__ __align__(16) unsigned short xs[64 * 72];
    __shared__ __align__(16) unsigned short hid[64 * 72];
    const int t = threadIdx.x, lane = t & 63, wave = t >> 6;
    const int e0 = blockIdx.x * 64 + wave * 16;
    unsigned short* xw = xs + wave * 16 * 72;
    unsigned short* hw = hid + wave * 16 * 72;
    const int l15 = lane & 15, q = lane >> 4;

    // stage 16 edges' feats fp32 -> bf16 (standard cols)
    {
        int r = lane >> 2, c4 = lane & 3;
        #pragma unroll
        for (int i = 0; i < 4; ++i) {
            int col = (c4 + i * 4) * 4;
            float4 v = *(const float4*)(efeat + (size_t)(e0 + r) * 64 + col);
            unsigned short* dp = xw + r * 72 + col;
            dp[0] = f2bf(v.x); dp[1] = f2bf(v.y); dp[2] = f2bf(v.z); dp[3] = f2bf(v.w);
        }
    }
    int sj[4], dj[4];
    #pragma unroll
    for (int j = 0; j < 4; ++j) {                // this lane's 4 edge rows
        sj[j] = src[e0 + q * 4 + j];
        dj[j] = dst[e0 + q * 4 + j];
    }
    // prefetch gathers NOW: permuted storage -> one 8B load covers this lane's
    // 4 cols (t4*16+l15). Consumed after the we-MLP, ~2k cycles later.
    u16x4 va[4], vb[4];
    #pragma unroll
    for (int j = 0; j < 4; ++j) {
        va[j] = *(const u16x4*)(hs + (size_t)sj[j] * 64 + l15 * 4);
        vb[j] = *(const u16x4*)(hd + (size_t)dj[j] * 64 + l15 * 4);
    }
    wave_sync();                                       // xs staged

    f32x4 acc[4], ef[4];
    mfma_layer(xw, wbf + 4 * 4096, be1, lane, acc);    // we layer 1 (std)
    wave_sync();
    mish_to_lds_perm(acc, hw, lane);
    wave_sync();                                       // hid written
    mfma_layer(hw, wbf + 5 * 4096, be2, lane, ef);     // we layer 2 (K-perm) -> ef
    wave_sync();                                       // retire xs/hid reads (WAR)

    // Coulomb: exact np op order for num/den; divide -> v_rcp (~1 ulp, result is
    // bf16-rounded anyway). SINGULARITY GUARD: den==0 (ef underflow) -> h=0,
    // matching the reference to ~1e-15 there (see prior session note); clamp
    // keeps every h finite in bf16.
    #pragma unroll
    for (int j = 0; j < 4; ++j) {
        u16x4 hv;
        #pragma unroll
        for (int t4 = 0; t4 < 4; ++t4) {
            float a = bf2f(va[j][t4]);               // hs[src][t4*16+l15]
            float b = bf2f(vb[j][t4]);               // hd[dst][t4*16+l15]
            float den = (C_A * ef[t4][j]) * C_B;
            float num = (a * b) * C_E2;
            float h = (den != 0.0f) ? num * __builtin_amdgcn_rcpf(den) : 0.0f;
            h = fminf(fmaxf(h, -1e30f), 1e30f);      // bf16-safe (no inf ever)
            hv[t4] = f2bf(h);
        }
        *(u16x4*)(xw + (q * 4 + j) * 72 + l15 * 4) = hv;   // h_nodes, permuted, 8B
    }
    wave_sync();                                       // xs (h_nodes) written

    mfma_layer(xw, wbf + 6 * 4096, bm1, lane, acc);    // wm layer 1 (K-perm)
    wave_sync();
    mish_to_lds_perm(acc, hw, lane);
    wave_sync();                                       // hid written
    mfma_layer(hw, wbf + 7 * 4096, bm2, lane, acc);    // wm layer 2 (K-perm) -> msgs

    // scatter-sum: per (t4,j) the 16 lanes hit one node's contiguous 64B
    #pragma unroll
    for (int j = 0; j < 4; ++j) {
        float* p = out + (size_t)dj[j] * 64;
        #pragma unroll
        for (int t4 = 0; t4 < 4; ++t4)
            atomicAdd(p + t4 * 16 + l15, acc[t4][j]);
    }
}

// K3: out = softplus(node_feats + out), float4
__global__ __launch_bounds__(256) void finalize_kernel(
    const float* __restrict__ nf, float* __restrict__ out)
{
    int g = blockIdx.x * 256 + threadIdx.x;
    float4 a = ((const float4*)nf)[g];
    float4 h = ((float4*)out)[g];
    float4 o;
    o.x = softplus_f(a.x + h.x);
    o.y = softplus_f(a.y + h.y);
    o.z = softplus_f(a.z + h.z);
    o.w = softplus_f(a.w + h.w);
    ((float4*)out)[g] = o;
}

extern "C" void kernel_launch(void* const* d_in, const int* in_sizes, int n_in,
                              void* d_out, int out_size, void* d_ws, size_t ws_size,
                              hipStream_t stream)
{
    const float* node_feats = (const float*)d_in[0];
    const float* edge_feats = (const float*)d_in[1];
    const int*   src        = (const int*)d_in[2];
    const int*   dst        = (const int*)d_in[3];
    const float* ws_w1 = (const float*)d_in[4];
    const float* ws_b1 = (const float*)d_in[5];
    const float* ws_w2 = (const float*)d_in[6];
    const float* ws_b2 = (const float*)d_in[7];
    const float* wd_w1 = (const float*)d_in[8];
    const float* wd_b1 = (const float*)d_in[9];
    const float* wd_w2 = (const float*)d_in[10];
    const float* wd_b2 = (const float*)d_in[11];
    const float* we_w1 = (const float*)d_in[12];
    const float* we_b1 = (const float*)d_in[13];
    const float* we_w2 = (const float*)d_in[14];
    const float* we_b2 = (const float*)d_in[15];
    const float* wm_w1 = (const float*)d_in[16];
    const float* wm_b1 = (const float*)d_in[17];
    const float* wm_w2 = (const float*)d_in[18];
    const float* wm_b2 = (const float*)d_in[19];

    // ws layout: wbf (8*4096 bf16 = 64KB) | hs (12.8MB bf16) | hd (12.8MB bf16)
    unsigned short* wbf = (unsigned short*)d_ws;
    unsigned short* hs  = wbf + 8 * 4096;
    unsigned short* hd  = hs + (size_t)NNODES * 64;

    convert_w_kernel<<<32, 256, 0, stream>>>(
        ws_w1, ws_w2, wd_w1, wd_w2, we_w1, we_w2, wm_w1, wm_w2, wbf);

    node_mlp_kernel<<<(NNODES + 63) / 64, 256, 0, stream>>>(
        node_feats, wbf, ws_b1, ws_b2, wd_b1, wd_b2, hs, hd, (float*)d_out);

    edge_kernel<<<NEDGES / 64, 256, 0, stream>>>(
        edge_feats, hs, hd, src, dst, wbf, we_b1, we_b2, wm_b1, wm_b2, (float*)d_out);

    finalize_kernel<<<(NNODES * 64) / (256 * 4), 256, 0, stream>>>(
        node_feats, (float*)d_out);
}